// Round 10
// baseline (291.191 us; speedup 1.0000x reference)
//
#include <hip/hip_runtime.h>
#include <hip/hip_bf16.h>

#define B_  8
#define D_  192
#define H_  64
#define W_  64
#define L_  4096
#define K_  4
#define N_  16
#define R_  6
#define C_  38   // R + 2N
#define CP  40   // padded x_dbl row (floats)
#define CL_ 64   // scan chunk length
#define NC_ 64   // number of chunks (L_/CL_)

using bf16 = __hip_bfloat16;
typedef float v2f __attribute__((ext_vector_type(2)));
typedef short v8s __attribute__((ext_vector_type(8)));   // 8 bf16 (4 VGPRs)
typedef float f32x4 __attribute__((ext_vector_type(4))); // MFMA acc

static __device__ __forceinline__ float softplus_f(float x) {
    return fmaxf(x, 0.f) + __logf(1.f + __expf(-fabsf(x)));
}
static __device__ __forceinline__ float bflo(unsigned u) {
    return __uint_as_float(u << 16);
}
// exp2 on the VALU pipe (no v_exp_f32). The trans pipe is the saturated
// resource in scanA/corr (18 trans/step x 16cy = 70% of the 412cy/step issue
// budget — R9 post-mortem); moving a fraction of the exps to VALU balances
// the pipes. Degree-6 Taylor on [-0.5,0.5] after rndne range-reduction;
// relative err ~2e-8. Input must be <= 0 (A<0, delta>=0); clamp at -126.
static __device__ __forceinline__ float exp2_poly(float x) {
    x = fmaxf(x, -126.f);
    float r = __builtin_rintf(x);          // v_rndne_f32
    float f = x - r;
    float p = 1.5403530e-4f;
    p = fmaf(p, f, 1.3333558e-3f);
    p = fmaf(p, f, 9.6181291e-3f);
    p = fmaf(p, f, 5.5504109e-2f);
    p = fmaf(p, f, 2.4022651e-1f);
    p = fmaf(p, f, 6.9314718e-1f);
    p = fmaf(p, f, 1.0f);
    int e = (int)r;
    float s = __int_as_float((unsigned)(e + 127) << 23);
    return p * s;
}

// ---------------------------------------------------------------------------
// Kernel 1: transpose x (B,D,L) -> xp0b (B,L,D) row-major scan order and
// xp1b (B,L1,D) col-major order (l1 = w*H + h), bf16.
// ---------------------------------------------------------------------------
__global__ __launch_bounds__(256) void k_transpose(const float* __restrict__ x,
                                                   bf16* __restrict__ xp0b,
                                                   bf16* __restrict__ xp1b) {
    __shared__ float tile[32][33];
    int bi = blockIdx.x;
    int pg = bi & 127;          // L/32 tiles
    int dg = (bi >> 7) % 6;     // D/32 tiles
    int b  = bi / (128 * 6);
    int tx = threadIdx.x & 31;
    int ty = threadIdx.x >> 5;  // 0..7
    size_t xbase = (size_t)b * D_ * L_;
    #pragma unroll
    for (int i = 0; i < 4; i++) {
        int d = dg * 32 + ty + i * 8;
        tile[ty + i * 8][tx] = x[xbase + (size_t)d * L_ + pg * 32 + tx];
    }
    __syncthreads();
    #pragma unroll
    for (int i = 0; i < 4; i++) {
        int p = pg * 32 + ty + i * 8;
        float v = tile[tx][ty + i * 8];
        bf16 vb = __float2bfloat16(v);
        int d = dg * 32 + tx;
        xp0b[((size_t)b * L_ + p) * D_ + d] = vb;
        int hh = p >> 6, ww = p & 63;
        int r = ww * 64 + hh;   // l1 index
        xp1b[((size_t)b * L_ + r) * D_ + d] = vb;
    }
}

// ---------------------------------------------------------------------------
// Kernel 2 (MFMA): x_dbl[b,k,l,c] = sum_d xs[b,k,d,l] * W[k,c,d]
// ---------------------------------------------------------------------------
__global__ __launch_bounds__(256) void k_proj(const bf16* __restrict__ xp0b,
                                              const bf16* __restrict__ xp1b,
                                              const float* __restrict__ Wp,   // (K,38,192) f32
                                              float* __restrict__ xdbl) {     // (B,K,L,CP)
    __shared__ __align__(16) unsigned short xt[64 * 200];
    __shared__ __align__(16) unsigned short wt[48 * 200];
    int blk  = blockIdx.x;
    int tile = blk & 63;
    int bk   = blk >> 6;
    int k    = bk & 3;
    int b    = bk >> 2;
    const bf16* xpb = (k & 1) ? xp1b : xp0b;
    int g0 = (k < 2) ? tile * 64 : (L_ - 64 - tile * 64);

    unsigned* wtu = (unsigned*)wt;
    for (int i = threadIdx.x; i < 1000; i += 256) wtu[3800 + i] = 0u;
    const float2* wsrc = (const float2*)(Wp + (size_t)k * C_ * D_);
    for (int i = threadIdx.x; i < 3648; i += 256) {   // 38*96 float2
        float2 wv2 = wsrc[i];
        int c = i / 96, dp = i % 96;
        bf16 b0 = __float2bfloat16(wv2.x), b1 = __float2bfloat16(wv2.y);
        unsigned pack = ((unsigned)(*(unsigned short*)&b1) << 16) |
                        (unsigned)(*(unsigned short*)&b0);
        wtu[c * 100 + dp] = pack;
    }
    const uint4* src = (const uint4*)(xpb + ((size_t)b * L_ + g0) * D_);
    for (int i = threadIdx.x; i < 1536; i += 256) {
        uint4 v = src[i];
        int row = i / 24, cg = i % 24;
        int rr = (k < 2) ? row : 63 - row;
        *((uint4*)(xt + rr * 200 + cg * 8)) = v;
    }
    __syncthreads();

    int wv   = threadIdx.x >> 6;
    int lane = threadIdx.x & 63;
    int m0   = wv * 16;
    int mrow = lane & 15;
    int kq   = lane >> 4;

    f32x4 acc[3];
    #pragma unroll
    for (int nt = 0; nt < 3; nt++) acc[nt] = (f32x4){0.f, 0.f, 0.f, 0.f};

    const unsigned short* arow = xt + (m0 + mrow) * 200 + kq * 8;
    const unsigned short* brow = wt + mrow * 200 + kq * 8;
    #pragma unroll
    for (int kt = 0; kt < 6; kt++) {
        v8s af = *(const v8s*)(arow + kt * 32);
        #pragma unroll
        for (int nt = 0; nt < 3; nt++) {
            v8s bf = *(const v8s*)(brow + nt * 16 * 200 + kt * 32);
            acc[nt] = __builtin_amdgcn_mfma_f32_16x16x32_bf16(af, bf, acc[nt], 0, 0, 0);
        }
    }

    int l0g = tile * 64;
    #pragma unroll
    for (int nt = 0; nt < 3; nt++) {
        int c = nt * 16 + mrow;
        if (c < C_) {
            #pragma unroll
            for (int r = 0; r < 4; r++) {
                int m = m0 + kq * 4 + r;
                xdbl[((size_t)bk * L_ + l0g + m) * CP + c] = acc[nt][r];
            }
        }
    }
}

// ---------------------------------------------------------------------------
// Kernel 3 (scanA): ONE scan pass from h=0 per chunk. Emits
// y_local = C.h_local + Ds*u (bf16) and chunk summary P=exp(A*S_64), Hloc.
// No S store — k_corr recomputes S from xdbl (bit-identical f32 sequence).
//
// R10: trans/VALU pipe rebalance. Evidence: VALUBusy x dur == 66 µs across
// ALL six structural variants (R0-R9), unresponsive to pk-fma instruction
// reduction -> the trans pipe binds: 18 trans/step x 16cy (wave64 1/4-rate)
// = 288 of the measured 412 cy/step. Fix: 4 of the 16 inner exps move to
// exp2_poly on the VALU pipe -> trans 224cy, VALU ~234cy, balanced.
// softplus/S chain untouched (must stay bit-identical to k_corr).
// ---------------------------------------------------------------------------
__global__ __launch_bounds__(192) void k_scanA(const float* __restrict__ xdbl,
                                               const bf16* __restrict__ xp0b,
                                               const bf16* __restrict__ xp1b,
                                               const float* __restrict__ dtw,   // (K,D,R)
                                               const float* __restrict__ dtb,   // (K,D)
                                               const float* __restrict__ Alog,  // (K*D,N)
                                               const float* __restrict__ Dsk,   // (K*D,)
                                               bf16* __restrict__ Pst,
                                               bf16* __restrict__ Hloc,
                                               bf16* __restrict__ ys) {         // (B,K,L,D)
    __shared__ __align__(16) unsigned short ut[CL_ * D_];  // 24.6 KB
    int blk = blockIdx.x;
    int c   = blk & (NC_ - 1);
    int bk  = blk >> 6;
    int k   = bk & 3;
    int b   = bk >> 2;
    int d   = threadIdx.x;

    int l0 = c * CL_;
    const bf16* xpb = (k & 1) ? xp1b : xp0b;
    int base_lu = (k < 2) ? l0 : (L_ - CL_ - l0);
    {
        const uint4* usrc = (const uint4*)(xpb + ((size_t)b * L_ + base_lu) * D_);
        uint4* udst = (uint4*)ut;
        #pragma unroll
        for (int i = 0; i < 8; i++) udst[threadIdx.x + i * 192] = usrc[threadIdx.x + i * 192];
    }

    v2f A2[8];     // A * log2(e) pairs, for exp2
    #pragma unroll
    for (int i = 0; i < 8; i++) {
        A2[i].x = -__expf(Alog[((size_t)(k * D_ + d)) * N_ + 2*i])   * 1.44269504f;
        A2[i].y = -__expf(Alog[((size_t)(k * D_ + d)) * N_ + 2*i+1]) * 1.44269504f;
    }
    float wr[R_];
    #pragma unroll
    for (int r = 0; r < R_; r++) wr[r] = dtw[(k * D_ + d) * R_ + r];
    float bias = dtb[k * D_ + d];
    float DsV  = Dsk[k * D_ + d];

    v2f h[8];
    #pragma unroll
    for (int i = 0; i < 8; i++) { h[i].x = 0.f; h[i].y = 0.f; }
    float S = 0.f;
    const float* rb = xdbl + ((size_t)bk * L_ + l0) * CP;
    bf16* yp  = ys   + ((size_t)bk * L_ + l0) * D_ + d;

    int uidx  = ((k < 2) ? 0 : (CL_ - 1)) * D_ + d;
    int ustep = (k < 2) ? D_ : -D_;
    __syncthreads();

    #pragma unroll 2
    for (int s = 0; s < CL_; s++) {
        const float4* r4 = (const float4*)(rb + s * CP);   // block-uniform -> s_load
        float4 q0 = r4[0], q1 = r4[1], q2 = r4[2], q3 = r4[3], q4 = r4[4];
        float4 q5 = r4[5], q6 = r4[6], q7 = r4[7], q8 = r4[8], q9 = r4[9];
        float dpre = bias + wr[0]*q0.x + wr[1]*q0.y + wr[2]*q0.z + wr[3]*q0.w
                          + wr[4]*q1.x + wr[5]*q1.y;
        float delta = softplus_f(dpre);
        float u = bflo(ut[uidx]);  uidx += ustep;          // ds_read_u16
        float du = delta * u;
        S += delta;
        v2f Bv[8] = {{q1.z,q1.w},{q2.x,q2.y},{q2.z,q2.w},{q3.x,q3.y},
                     {q3.z,q3.w},{q4.x,q4.y},{q4.z,q4.w},{q5.x,q5.y}};
        v2f Cv[8] = {{q5.z,q5.w},{q6.x,q6.y},{q6.z,q6.w},{q7.x,q7.y},
                     {q7.z,q7.w},{q8.x,q8.y},{q8.z,q8.w},{q9.x,q9.y}};
        v2f dl2; dl2.x = delta; dl2.y = delta;
        v2f du2; du2.x = du;    du2.y = du;
        v2f y2; y2.x = 0.f; y2.y = 0.f;
        #pragma unroll
        for (int i = 0; i < 8; i++) {
            v2f t = A2[i] * dl2;
            v2f dA;
            if (i < 6) {                       // trans pipe (12 exps)
                dA.x = __builtin_amdgcn_exp2f(t.x);
                dA.y = __builtin_amdgcn_exp2f(t.y);
            } else {                           // VALU pipe (4 exps)
                dA.x = exp2_poly(t.x);
                dA.y = exp2_poly(t.y);
            }
            v2f bdu = Bv[i] * du2;
            h[i] = __builtin_elementwise_fma(dA, h[i], bdu);   // v_pk_fma_f32
            y2   = __builtin_elementwise_fma(h[i], Cv[i], y2); // v_pk_fma_f32
        }
        float y = y2.x + y2.y;
        *yp = __float2bfloat16(y + u * DsV);
        yp += D_;
    }
    size_t o = ((size_t)blk * D_ + d) * N_;   // blk == bk*NC_ + c
    #pragma unroll
    for (int i = 0; i < 8; i++) {
        v2f t = A2[i] * S;
        Pst[o + 2*i]   = __float2bfloat16(__builtin_amdgcn_exp2f(t.x));
        Pst[o + 2*i+1] = __float2bfloat16(__builtin_amdgcn_exp2f(t.y));
        Hloc[o + 2*i]   = __float2bfloat16(h[i].x);
        Hloc[o + 2*i+1] = __float2bfloat16(h[i].y);
    }
}

// ---------------------------------------------------------------------------
// Kernel 4 (pass 2): chunk-prefix scan over NC_ chunks per (b,k,d,n).
// ---------------------------------------------------------------------------
__global__ __launch_bounds__(256) void k_pass2(const bf16* __restrict__ Pst,
                                               const bf16* __restrict__ Hloc,
                                               bf16* __restrict__ Hin) {
    int idx = blockIdx.x * 256 + threadIdx.x;   // over B*K*D*N
    int bk  = idx / (D_ * N_);
    int dn  = idx % (D_ * N_);
    float hh = 0.f;
    for (int c = 0; c < NC_; c++) {
        size_t o = ((size_t)bk * NC_ + c) * (D_ * N_) + dn;
        Hin[o] = __float2bfloat16(hh);
        hh = __bfloat162float(Pst[o]) * hh + __bfloat162float(Hloc[o]);
    }
}

// ---------------------------------------------------------------------------
// Kernel 5 (corr): ys += C_l . (exp(A*S_l) * h_in). S is recomputed from
// xdbl's dt columns (scalar-prefetch path; bit-identical to scanA) — no
// per-step vector-load dependency. Per-wave ballot exits the dead tail
// (exp(A*S) < 2^-18) early, typically ~18-25 of 64 steps alive.
// R10: same 12/4 trans/poly split as scanA.
// ---------------------------------------------------------------------------
__global__ __launch_bounds__(192) void k_corr(const float* __restrict__ xdbl,
                                              const float* __restrict__ dtw,   // (K,D,R)
                                              const float* __restrict__ dtb,   // (K,D)
                                              const float* __restrict__ Alog,
                                              const bf16* __restrict__ Hin,
                                              bf16* __restrict__ ys) {
    int blk = blockIdx.x;
    int c   = blk & (NC_ - 1);
    if (c == 0) return;                        // h_in == 0 for first chunk
    int bk  = blk >> 6;
    int k   = bk & 3;
    int d   = threadIdx.x;

    v2f A22[8];
    float aMax = -1e30f;
    #pragma unroll
    for (int i = 0; i < 8; i++) {
        float a0 = -__expf(Alog[((size_t)(k * D_ + d)) * N_ + 2*i])   * 1.44269504f;
        float a1 = -__expf(Alog[((size_t)(k * D_ + d)) * N_ + 2*i+1]) * 1.44269504f;
        A22[i].x = a0; A22[i].y = a1;
        aMax = fmaxf(aMax, fmaxf(a0, a1));
    }
    float wr[R_];
    #pragma unroll
    for (int r = 0; r < R_; r++) wr[r] = dtw[(k * D_ + d) * R_ + r];
    float bias = dtb[k * D_ + d];

    v2f g2[8];
    size_t o = ((size_t)blk * D_ + d) * N_;
    #pragma unroll
    for (int i = 0; i < 8; i++) {
        g2[i].x = __bfloat162float(Hin[o + 2*i]);
        g2[i].y = __bfloat162float(Hin[o + 2*i+1]);
    }

    int l0 = c * CL_;
    const float* rb = xdbl + ((size_t)bk * L_ + l0) * CP;   // block-uniform
    bf16* yp = ys + ((size_t)bk * L_ + l0) * D_ + d;

    float S = 0.f;
    for (int s = 0; s < CL_; s++) {
        const float4* r4 = (const float4*)(rb + s * CP);    // s_load path
        float4 q0 = r4[0], q1 = r4[1];
        float dpre = bias + wr[0]*q0.x + wr[1]*q0.y + wr[2]*q0.z + wr[3]*q0.w
                          + wr[4]*q1.x + wr[5]*q1.y;
        S += softplus_f(dpre);                              // identical to scanA
        bool alive = (aMax * S > -18.f);       // 2^-18 ~ 4e-6: below bf16 noise
        if (__ballot(alive) == 0ull) break;
        const float4* c4 = (const float4*)(rb + s * CP + 20);  // C part
        float4 c5 = c4[0], c6 = c4[1], c7 = c4[2], c8 = c4[3], c9 = c4[4];
        v2f C2[8] = {{c5.z,c5.w},{c6.x,c6.y},{c6.z,c6.w},{c7.x,c7.y},
                     {c7.z,c7.w},{c8.x,c8.y},{c8.z,c8.w},{c9.x,c9.y}};
        v2f S2; S2.x = S; S2.y = S;
        v2f acc2; acc2.x = 0.f; acc2.y = 0.f;
        #pragma unroll
        for (int i = 0; i < 8; i++) {
            v2f t = A22[i] * S2;
            v2f e;
            if (i < 6) {
                e.x = __builtin_amdgcn_exp2f(t.x);
                e.y = __builtin_amdgcn_exp2f(t.y);
            } else {
                e.x = exp2_poly(t.x);
                e.y = exp2_poly(t.y);
            }
            v2f eg = e * g2[i];
            acc2 = __builtin_elementwise_fma(C2[i], eg, acc2);  // v_pk_fma_f32
        }
        float acc = acc2.x + acc2.y;
        float y = __bfloat162float(*yp) + acc;
        *yp = __float2bfloat16(y);
        yp += D_;
    }
}

// ---------------------------------------------------------------------------
// Kernel 6: cross-merge (4 directions) + LayerNorm over D, output (B,H,W,D)
// ---------------------------------------------------------------------------
__global__ __launch_bounds__(192) void k_merge_ln(const bf16* __restrict__ ys,
                                                  const float* __restrict__ gw,
                                                  const float* __restrict__ gb,
                                                  float* __restrict__ out) {
    int p = blockIdx.x & (L_ - 1);
    int b = blockIdx.x >> 12;     // L_ = 4096
    int d = threadIdx.x;
    int hh = p >> 6, ww = p & 63;
    int l1 = ww * 64 + hh;
    size_t base = (size_t)b * K_ * L_ * D_;
    float v = __bfloat162float(ys[base + ((size_t)0 * L_ + p) * D_ + d])
            + __bfloat162float(ys[base + ((size_t)2 * L_ + (L_ - 1 - p)) * D_ + d])
            + __bfloat162float(ys[base + ((size_t)1 * L_ + l1) * D_ + d])
            + __bfloat162float(ys[base + ((size_t)3 * L_ + (L_ - 1 - l1)) * D_ + d]);
    float s1 = v, s2 = v * v;
    #pragma unroll
    for (int off = 32; off; off >>= 1) {
        s1 += __shfl_down(s1, off);
        s2 += __shfl_down(s2, off);
    }
    __shared__ float aS[3], aQ[3];
    int wid = d >> 6, lane = d & 63;
    if (lane == 0) { aS[wid] = s1; aQ[wid] = s2; }
    __syncthreads();
    float ts1 = aS[0] + aS[1] + aS[2];
    float ts2 = aQ[0] + aQ[1] + aQ[2];
    float mean = ts1 * (1.f / 192.f);
    float var  = ts2 * (1.f / 192.f) - mean * mean;
    float inv  = rsqrtf(var + 1e-5f);
    out[((size_t)b * L_ + p) * D_ + d] = (v - mean) * inv * gw[d] + gb[d];
}

// ---------------------------------------------------------------------------
extern "C" void kernel_launch(void* const* d_in, const int* in_sizes, int n_in,
                              void* d_out, int out_size, void* d_ws, size_t ws_size,
                              hipStream_t stream) {
    const float* x    = (const float*)d_in[0];
    const float* Wp   = (const float*)d_in[1];
    const float* dtw  = (const float*)d_in[2];
    const float* dtb  = (const float*)d_in[3];
    const float* Alog = (const float*)d_in[4];
    const float* Dsk  = (const float*)d_in[5];
    const float* gw   = (const float*)d_in[6];
    const float* gb   = (const float*)d_in[7];
    float* out = (float*)d_out;

    char* ws = (char*)d_ws;
    const size_t S1b = (size_t)B_ * L_ * D_ * 2;            // 12.6 MB (xp0b/xp1b)
    const size_t Sx  = (size_t)B_ * K_ * L_ * CP * 4;       // 21.0 MB (xdbl)
    const size_t Ss  = (size_t)B_ * K_ * NC_ * D_ * N_ * 2; // 12.6 MB (P/Hloc/Hin)
    char* p = ws;
    bf16*  xp0b = (bf16*)p;   p += S1b;
    bf16*  xp1b = (bf16*)p;   p += S1b;
    float* xdbl = (float*)p;  p += Sx;
    bf16*  Pst  = (bf16*)p;   p += Ss;
    bf16*  Hloc = (bf16*)p;   p += Ss;
    bf16*  Hin  = (bf16*)p;   p += Ss;
    bf16*  ys   = (bf16*)p;   // 50.3 MB; total ~135 MB

    k_transpose<<<B_ * 6 * 128, 256, 0, stream>>>(x, xp0b, xp1b);
    k_proj<<<B_ * K_ * (L_ / 64), 256, 0, stream>>>(xp0b, xp1b, Wp, xdbl);
    k_scanA<<<B_ * K_ * NC_, 192, 0, stream>>>(xdbl, xp0b, xp1b, dtw, dtb, Alog, Dsk,
                                               Pst, Hloc, ys);
    k_pass2<<<(B_ * K_ * D_ * N_) / 256, 256, 0, stream>>>(Pst, Hloc, Hin);
    k_corr<<<B_ * K_ * NC_, 192, 0, stream>>>(xdbl, dtw, dtb, Alog, Hin, ys);
    k_merge_ln<<<B_ * L_, 192, 0, stream>>>(ys, gw, gb, out);
}

// Round 11
// 255.844 us; speedup vs baseline: 1.1382x; 1.1382x over previous
//
#include <hip/hip_runtime.h>
#include <hip/hip_bf16.h>

#define B_  8
#define D_  192
#define H_  64
#define W_  64
#define L_  4096
#define K_  4
#define N_  16
#define R_  6
#define C_  38   // R + 2N
#define CP  40   // padded x_dbl row (floats)
#define CL_ 64   // scan chunk length
#define NC_ 64   // number of chunks (L_/CL_)

using bf16 = __hip_bfloat16;
typedef float v2f __attribute__((ext_vector_type(2)));
typedef short v8s __attribute__((ext_vector_type(8)));   // 8 bf16 (4 VGPRs)
typedef float f32x4 __attribute__((ext_vector_type(4))); // MFMA acc

static __device__ __forceinline__ float softplus_f(float x) {
    return fmaxf(x, 0.f) + __logf(1.f + __expf(-fabsf(x)));
}
static __device__ __forceinline__ float bflo(unsigned u) {
    return __uint_as_float(u << 16);
}

// ---------------------------------------------------------------------------
// Kernel 1: transpose x (B,D,L) -> xp0b (B,L,D) row-major scan order and
// xp1b (B,L1,D) col-major order (l1 = w*H + h), bf16.
// ---------------------------------------------------------------------------
__global__ __launch_bounds__(256) void k_transpose(const float* __restrict__ x,
                                                   bf16* __restrict__ xp0b,
                                                   bf16* __restrict__ xp1b) {
    __shared__ float tile[32][33];
    int bi = blockIdx.x;
    int pg = bi & 127;          // L/32 tiles
    int dg = (bi >> 7) % 6;     // D/32 tiles
    int b  = bi / (128 * 6);
    int tx = threadIdx.x & 31;
    int ty = threadIdx.x >> 5;  // 0..7
    size_t xbase = (size_t)b * D_ * L_;
    #pragma unroll
    for (int i = 0; i < 4; i++) {
        int d = dg * 32 + ty + i * 8;
        tile[ty + i * 8][tx] = x[xbase + (size_t)d * L_ + pg * 32 + tx];
    }
    __syncthreads();
    #pragma unroll
    for (int i = 0; i < 4; i++) {
        int p = pg * 32 + ty + i * 8;
        float v = tile[tx][ty + i * 8];
        bf16 vb = __float2bfloat16(v);
        int d = dg * 32 + tx;
        xp0b[((size_t)b * L_ + p) * D_ + d] = vb;
        int hh = p >> 6, ww = p & 63;
        int r = ww * 64 + hh;   // l1 index
        xp1b[((size_t)b * L_ + r) * D_ + d] = vb;
    }
}

// ---------------------------------------------------------------------------
// Kernel 2 (MFMA): x_dbl[b,k,l,c] = sum_d xs[b,k,d,l] * W[k,c,d]
// ---------------------------------------------------------------------------
__global__ __launch_bounds__(256) void k_proj(const bf16* __restrict__ xp0b,
                                              const bf16* __restrict__ xp1b,
                                              const float* __restrict__ Wp,   // (K,38,192) f32
                                              float* __restrict__ xdbl) {     // (B,K,L,CP)
    __shared__ __align__(16) unsigned short xt[64 * 200];
    __shared__ __align__(16) unsigned short wt[48 * 200];
    int blk  = blockIdx.x;
    int tile = blk & 63;
    int bk   = blk >> 6;
    int k    = bk & 3;
    int b    = bk >> 2;
    const bf16* xpb = (k & 1) ? xp1b : xp0b;
    int g0 = (k < 2) ? tile * 64 : (L_ - 64 - tile * 64);

    unsigned* wtu = (unsigned*)wt;
    for (int i = threadIdx.x; i < 1000; i += 256) wtu[3800 + i] = 0u;
    const float2* wsrc = (const float2*)(Wp + (size_t)k * C_ * D_);
    for (int i = threadIdx.x; i < 3648; i += 256) {   // 38*96 float2
        float2 wv2 = wsrc[i];
        int c = i / 96, dp = i % 96;
        bf16 b0 = __float2bfloat16(wv2.x), b1 = __float2bfloat16(wv2.y);
        unsigned pack = ((unsigned)(*(unsigned short*)&b1) << 16) |
                        (unsigned)(*(unsigned short*)&b0);
        wtu[c * 100 + dp] = pack;
    }
    const uint4* src = (const uint4*)(xpb + ((size_t)b * L_ + g0) * D_);
    for (int i = threadIdx.x; i < 1536; i += 256) {
        uint4 v = src[i];
        int row = i / 24, cg = i % 24;
        int rr = (k < 2) ? row : 63 - row;
        *((uint4*)(xt + rr * 200 + cg * 8)) = v;
    }
    __syncthreads();

    int wv   = threadIdx.x >> 6;
    int lane = threadIdx.x & 63;
    int m0   = wv * 16;
    int mrow = lane & 15;
    int kq   = lane >> 4;

    f32x4 acc[3];
    #pragma unroll
    for (int nt = 0; nt < 3; nt++) acc[nt] = (f32x4){0.f, 0.f, 0.f, 0.f};

    const unsigned short* arow = xt + (m0 + mrow) * 200 + kq * 8;
    const unsigned short* brow = wt + mrow * 200 + kq * 8;
    #pragma unroll
    for (int kt = 0; kt < 6; kt++) {
        v8s af = *(const v8s*)(arow + kt * 32);
        #pragma unroll
        for (int nt = 0; nt < 3; nt++) {
            v8s bf = *(const v8s*)(brow + nt * 16 * 200 + kt * 32);
            acc[nt] = __builtin_amdgcn_mfma_f32_16x16x32_bf16(af, bf, acc[nt], 0, 0, 0);
        }
    }

    int l0g = tile * 64;
    #pragma unroll
    for (int nt = 0; nt < 3; nt++) {
        int c = nt * 16 + mrow;
        if (c < C_) {
            #pragma unroll
            for (int r = 0; r < 4; r++) {
                int m = m0 + kq * 4 + r;
                xdbl[((size_t)bk * L_ + l0g + m) * CP + c] = acc[nt][r];
            }
        }
    }
}

// ---------------------------------------------------------------------------
// Kernel 3 (scanA): ONE scan pass from h=0 per chunk. Emits
// y_local = C.h_local + Ds*u (bf16) and chunk summary P=exp(A*S_64), Hloc.
// No S store — k_corr recomputes S from xdbl (bit-identical f32 sequence).
//
// R11 == R8 (verified best, 262.3 µs total / 100.5 µs scanA). Final model
// after 11 experiments: per-wave SERIAL issue = ~130cy VALU + 18 trans x
// 16cy = ~412 cy/step (matches VALUBusy x dur == 66 µs across ALL load-path
// /occupancy/pk variants; R10 proved trans+VALU are additive). The ~216
// cy/step residual is SMEM-latency bubble, unfillable by occupancy (22-41%
// tested) or restructuring (LDS/global/reg-prefetch all slower). Floor.
// ---------------------------------------------------------------------------
__global__ __launch_bounds__(192) void k_scanA(const float* __restrict__ xdbl,
                                               const bf16* __restrict__ xp0b,
                                               const bf16* __restrict__ xp1b,
                                               const float* __restrict__ dtw,   // (K,D,R)
                                               const float* __restrict__ dtb,   // (K,D)
                                               const float* __restrict__ Alog,  // (K*D,N)
                                               const float* __restrict__ Dsk,   // (K*D,)
                                               bf16* __restrict__ Pst,
                                               bf16* __restrict__ Hloc,
                                               bf16* __restrict__ ys) {         // (B,K,L,D)
    __shared__ __align__(16) unsigned short ut[CL_ * D_];  // 24.6 KB
    int blk = blockIdx.x;
    int c   = blk & (NC_ - 1);
    int bk  = blk >> 6;
    int k   = bk & 3;
    int b   = bk >> 2;
    int d   = threadIdx.x;

    int l0 = c * CL_;
    const bf16* xpb = (k & 1) ? xp1b : xp0b;
    int base_lu = (k < 2) ? l0 : (L_ - CL_ - l0);
    {
        const uint4* usrc = (const uint4*)(xpb + ((size_t)b * L_ + base_lu) * D_);
        uint4* udst = (uint4*)ut;
        #pragma unroll
        for (int i = 0; i < 8; i++) udst[threadIdx.x + i * 192] = usrc[threadIdx.x + i * 192];
    }

    v2f A2[8];     // A * log2(e) pairs, for exp2
    #pragma unroll
    for (int i = 0; i < 8; i++) {
        A2[i].x = -__expf(Alog[((size_t)(k * D_ + d)) * N_ + 2*i])   * 1.44269504f;
        A2[i].y = -__expf(Alog[((size_t)(k * D_ + d)) * N_ + 2*i+1]) * 1.44269504f;
    }
    float wr[R_];
    #pragma unroll
    for (int r = 0; r < R_; r++) wr[r] = dtw[(k * D_ + d) * R_ + r];
    float bias = dtb[k * D_ + d];
    float DsV  = Dsk[k * D_ + d];

    v2f h[8];
    #pragma unroll
    for (int i = 0; i < 8; i++) { h[i].x = 0.f; h[i].y = 0.f; }
    float S = 0.f;
    const float* rb = xdbl + ((size_t)bk * L_ + l0) * CP;
    bf16* yp  = ys   + ((size_t)bk * L_ + l0) * D_ + d;

    int uidx  = ((k < 2) ? 0 : (CL_ - 1)) * D_ + d;
    int ustep = (k < 2) ? D_ : -D_;
    __syncthreads();

    #pragma unroll 2
    for (int s = 0; s < CL_; s++) {
        const float4* r4 = (const float4*)(rb + s * CP);   // block-uniform -> s_load
        float4 q0 = r4[0], q1 = r4[1], q2 = r4[2], q3 = r4[3], q4 = r4[4];
        float4 q5 = r4[5], q6 = r4[6], q7 = r4[7], q8 = r4[8], q9 = r4[9];
        float dpre = bias + wr[0]*q0.x + wr[1]*q0.y + wr[2]*q0.z + wr[3]*q0.w
                          + wr[4]*q1.x + wr[5]*q1.y;
        float delta = softplus_f(dpre);
        float u = bflo(ut[uidx]);  uidx += ustep;          // ds_read_u16
        float du = delta * u;
        S += delta;
        v2f Bv[8] = {{q1.z,q1.w},{q2.x,q2.y},{q2.z,q2.w},{q3.x,q3.y},
                     {q3.z,q3.w},{q4.x,q4.y},{q4.z,q4.w},{q5.x,q5.y}};
        v2f Cv[8] = {{q5.z,q5.w},{q6.x,q6.y},{q6.z,q6.w},{q7.x,q7.y},
                     {q7.z,q7.w},{q8.x,q8.y},{q8.z,q8.w},{q9.x,q9.y}};
        v2f dl2; dl2.x = delta; dl2.y = delta;
        v2f du2; du2.x = du;    du2.y = du;
        v2f y2; y2.x = 0.f; y2.y = 0.f;
        #pragma unroll
        for (int i = 0; i < 8; i++) {
            v2f t = A2[i] * dl2;
            v2f dA;
            dA.x = __builtin_amdgcn_exp2f(t.x);
            dA.y = __builtin_amdgcn_exp2f(t.y);
            v2f bdu = Bv[i] * du2;
            h[i] = __builtin_elementwise_fma(dA, h[i], bdu);   // v_pk_fma_f32
            y2   = __builtin_elementwise_fma(h[i], Cv[i], y2); // v_pk_fma_f32
        }
        float y = y2.x + y2.y;
        *yp = __float2bfloat16(y + u * DsV);
        yp += D_;
    }
    size_t o = ((size_t)blk * D_ + d) * N_;   // blk == bk*NC_ + c
    #pragma unroll
    for (int i = 0; i < 8; i++) {
        v2f t = A2[i] * S;
        Pst[o + 2*i]   = __float2bfloat16(__builtin_amdgcn_exp2f(t.x));
        Pst[o + 2*i+1] = __float2bfloat16(__builtin_amdgcn_exp2f(t.y));
        Hloc[o + 2*i]   = __float2bfloat16(h[i].x);
        Hloc[o + 2*i+1] = __float2bfloat16(h[i].y);
    }
}

// ---------------------------------------------------------------------------
// Kernel 4 (pass 2): chunk-prefix scan over NC_ chunks per (b,k,d,n).
// ---------------------------------------------------------------------------
__global__ __launch_bounds__(256) void k_pass2(const bf16* __restrict__ Pst,
                                               const bf16* __restrict__ Hloc,
                                               bf16* __restrict__ Hin) {
    int idx = blockIdx.x * 256 + threadIdx.x;   // over B*K*D*N
    int bk  = idx / (D_ * N_);
    int dn  = idx % (D_ * N_);
    float hh = 0.f;
    for (int c = 0; c < NC_; c++) {
        size_t o = ((size_t)bk * NC_ + c) * (D_ * N_) + dn;
        Hin[o] = __float2bfloat16(hh);
        hh = __bfloat162float(Pst[o]) * hh + __bfloat162float(Hloc[o]);
    }
}

// ---------------------------------------------------------------------------
// Kernel 5 (corr): ys += C_l . (exp(A*S_l) * h_in). S is recomputed from
// xdbl's dt columns (scalar-prefetch path; bit-identical to scanA) — no
// per-step vector-load dependency. Per-wave ballot exits the dead tail early.
// R11: exit threshold 2^-18 -> 2^-13 (1.2e-4). Tail-sum error bound
// <= 16*|C|*|g|*2^-13 with geometric decay ~ 4e-3, vs absmax margin 0.117.
// Cuts live steps ~25-35%.
// ---------------------------------------------------------------------------
__global__ __launch_bounds__(192) void k_corr(const float* __restrict__ xdbl,
                                              const float* __restrict__ dtw,   // (K,D,R)
                                              const float* __restrict__ dtb,   // (K,D)
                                              const float* __restrict__ Alog,
                                              const bf16* __restrict__ Hin,
                                              bf16* __restrict__ ys) {
    int blk = blockIdx.x;
    int c   = blk & (NC_ - 1);
    if (c == 0) return;                        // h_in == 0 for first chunk
    int bk  = blk >> 6;
    int k   = bk & 3;
    int d   = threadIdx.x;

    v2f A22[8];
    float aMax = -1e30f;
    #pragma unroll
    for (int i = 0; i < 8; i++) {
        float a0 = -__expf(Alog[((size_t)(k * D_ + d)) * N_ + 2*i])   * 1.44269504f;
        float a1 = -__expf(Alog[((size_t)(k * D_ + d)) * N_ + 2*i+1]) * 1.44269504f;
        A22[i].x = a0; A22[i].y = a1;
        aMax = fmaxf(aMax, fmaxf(a0, a1));
    }
    float wr[R_];
    #pragma unroll
    for (int r = 0; r < R_; r++) wr[r] = dtw[(k * D_ + d) * R_ + r];
    float bias = dtb[k * D_ + d];

    v2f g2[8];
    size_t o = ((size_t)blk * D_ + d) * N_;
    #pragma unroll
    for (int i = 0; i < 8; i++) {
        g2[i].x = __bfloat162float(Hin[o + 2*i]);
        g2[i].y = __bfloat162float(Hin[o + 2*i+1]);
    }

    int l0 = c * CL_;
    const float* rb = xdbl + ((size_t)bk * L_ + l0) * CP;   // block-uniform
    bf16* yp = ys + ((size_t)bk * L_ + l0) * D_ + d;

    float S = 0.f;
    for (int s = 0; s < CL_; s++) {
        const float4* r4 = (const float4*)(rb + s * CP);    // s_load path
        float4 q0 = r4[0], q1 = r4[1];
        float dpre = bias + wr[0]*q0.x + wr[1]*q0.y + wr[2]*q0.z + wr[3]*q0.w
                          + wr[4]*q1.x + wr[5]*q1.y;
        S += softplus_f(dpre);                              // identical to scanA
        bool alive = (aMax * S > -13.f);       // 2^-13 ~ 1.2e-4: below bf16 noise
        if (__ballot(alive) == 0ull) break;
        const float4* c4 = (const float4*)(rb + s * CP + 20);  // C part
        float4 c5 = c4[0], c6 = c4[1], c7 = c4[2], c8 = c4[3], c9 = c4[4];
        v2f C2[8] = {{c5.z,c5.w},{c6.x,c6.y},{c6.z,c6.w},{c7.x,c7.y},
                     {c7.z,c7.w},{c8.x,c8.y},{c8.z,c8.w},{c9.x,c9.y}};
        v2f S2; S2.x = S; S2.y = S;
        v2f acc2; acc2.x = 0.f; acc2.y = 0.f;
        #pragma unroll
        for (int i = 0; i < 8; i++) {
            v2f t = A22[i] * S2;
            v2f e;
            e.x = __builtin_amdgcn_exp2f(t.x);
            e.y = __builtin_amdgcn_exp2f(t.y);
            v2f eg = e * g2[i];
            acc2 = __builtin_elementwise_fma(C2[i], eg, acc2);  // v_pk_fma_f32
        }
        float acc = acc2.x + acc2.y;
        float y = __bfloat162float(*yp) + acc;
        *yp = __float2bfloat16(y);
        yp += D_;
    }
}

// ---------------------------------------------------------------------------
// Kernel 6: cross-merge (4 directions) + LayerNorm over D, output (B,H,W,D)
// ---------------------------------------------------------------------------
__global__ __launch_bounds__(192) void k_merge_ln(const bf16* __restrict__ ys,
                                                  const float* __restrict__ gw,
                                                  const float* __restrict__ gb,
                                                  float* __restrict__ out) {
    int p = blockIdx.x & (L_ - 1);
    int b = blockIdx.x >> 12;     // L_ = 4096
    int d = threadIdx.x;
    int hh = p >> 6, ww = p & 63;
    int l1 = ww * 64 + hh;
    size_t base = (size_t)b * K_ * L_ * D_;
    float v = __bfloat162float(ys[base + ((size_t)0 * L_ + p) * D_ + d])
            + __bfloat162float(ys[base + ((size_t)2 * L_ + (L_ - 1 - p)) * D_ + d])
            + __bfloat162float(ys[base + ((size_t)1 * L_ + l1) * D_ + d])
            + __bfloat162float(ys[base + ((size_t)3 * L_ + (L_ - 1 - l1)) * D_ + d]);
    float s1 = v, s2 = v * v;
    #pragma unroll
    for (int off = 32; off; off >>= 1) {
        s1 += __shfl_down(s1, off);
        s2 += __shfl_down(s2, off);
    }
    __shared__ float aS[3], aQ[3];
    int wid = d >> 6, lane = d & 63;
    if (lane == 0) { aS[wid] = s1; aQ[wid] = s2; }
    __syncthreads();
    float ts1 = aS[0] + aS[1] + aS[2];
    float ts2 = aQ[0] + aQ[1] + aQ[2];
    float mean = ts1 * (1.f / 192.f);
    float var  = ts2 * (1.f / 192.f) - mean * mean;
    float inv  = rsqrtf(var + 1e-5f);
    out[((size_t)b * L_ + p) * D_ + d] = (v - mean) * inv * gw[d] + gb[d];
}

// ---------------------------------------------------------------------------
extern "C" void kernel_launch(void* const* d_in, const int* in_sizes, int n_in,
                              void* d_out, int out_size, void* d_ws, size_t ws_size,
                              hipStream_t stream) {
    const float* x    = (const float*)d_in[0];
    const float* Wp   = (const float*)d_in[1];
    const float* dtw  = (const float*)d_in[2];
    const float* dtb  = (const float*)d_in[3];
    const float* Alog = (const float*)d_in[4];
    const float* Dsk  = (const float*)d_in[5];
    const float* gw   = (const float*)d_in[6];
    const float* gb   = (const float*)d_in[7];
    float* out = (float*)d_out;

    char* ws = (char*)d_ws;
    const size_t S1b = (size_t)B_ * L_ * D_ * 2;            // 12.6 MB (xp0b/xp1b)
    const size_t Sx  = (size_t)B_ * K_ * L_ * CP * 4;       // 21.0 MB (xdbl)
    const size_t Ss  = (size_t)B_ * K_ * NC_ * D_ * N_ * 2; // 12.6 MB (P/Hloc/Hin)
    char* p = ws;
    bf16*  xp0b = (bf16*)p;   p += S1b;
    bf16*  xp1b = (bf16*)p;   p += S1b;
    float* xdbl = (float*)p;  p += Sx;
    bf16*  Pst  = (bf16*)p;   p += Ss;
    bf16*  Hloc = (bf16*)p;   p += Ss;
    bf16*  Hin  = (bf16*)p;   p += Ss;
    bf16*  ys   = (bf16*)p;   // 50.3 MB; total ~135 MB

    k_transpose<<<B_ * 6 * 128, 256, 0, stream>>>(x, xp0b, xp1b);
    k_proj<<<B_ * K_ * (L_ / 64), 256, 0, stream>>>(xp0b, xp1b, Wp, xdbl);
    k_scanA<<<B_ * K_ * NC_, 192, 0, stream>>>(xdbl, xp0b, xp1b, dtw, dtb, Alog, Dsk,
                                               Pst, Hloc, ys);
    k_pass2<<<(B_ * K_ * D_ * N_) / 256, 256, 0, stream>>>(Pst, Hloc, Hin);
    k_corr<<<B_ * K_ * NC_, 192, 0, stream>>>(xdbl, dtw, dtb, Alog, Hin, ys);
    k_merge_ln<<<B_ * L_, 192, 0, stream>>>(ys, gw, gb, out);
}

// Round 13
// 254.565 us; speedup vs baseline: 1.1439x; 1.0050x over previous
//
#include <hip/hip_runtime.h>
#include <hip/hip_bf16.h>

#define B_  8
#define D_  192
#define H_  64
#define W_  64
#define L_  4096
#define K_  4
#define N_  16
#define R_  6
#define C_  38   // R + 2N
#define CP  40   // padded x_dbl row (floats)
#define CL_ 64   // scan chunk length
#define NC_ 64   // number of chunks (L_/CL_)

using bf16 = __hip_bfloat16;
typedef float v2f __attribute__((ext_vector_type(2)));
typedef short v8s __attribute__((ext_vector_type(8)));   // 8 bf16 (4 VGPRs)
typedef float f32x4 __attribute__((ext_vector_type(4))); // MFMA acc

static __device__ __forceinline__ float softplus_f(float x) {
    return fmaxf(x, 0.f) + __logf(1.f + __expf(-fabsf(x)));
}
static __device__ __forceinline__ float bflo(unsigned u) {
    return __uint_as_float(u << 16);
}

// ---------------------------------------------------------------------------
// Kernel 1: transpose x (B,D,L) -> xp0b (B,L,D) row-major scan order and
// xp1b (B,L1,D) col-major order (l1 = w*H + h), bf16.
// ---------------------------------------------------------------------------
__global__ __launch_bounds__(256) void k_transpose(const float* __restrict__ x,
                                                   bf16* __restrict__ xp0b,
                                                   bf16* __restrict__ xp1b) {
    __shared__ float tile[32][33];
    int bi = blockIdx.x;
    int pg = bi & 127;          // L/32 tiles
    int dg = (bi >> 7) % 6;     // D/32 tiles
    int b  = bi / (128 * 6);
    int tx = threadIdx.x & 31;
    int ty = threadIdx.x >> 5;  // 0..7
    size_t xbase = (size_t)b * D_ * L_;
    #pragma unroll
    for (int i = 0; i < 4; i++) {
        int d = dg * 32 + ty + i * 8;
        tile[ty + i * 8][tx] = x[xbase + (size_t)d * L_ + pg * 32 + tx];
    }
    __syncthreads();
    #pragma unroll
    for (int i = 0; i < 4; i++) {
        int p = pg * 32 + ty + i * 8;
        float v = tile[tx][ty + i * 8];
        bf16 vb = __float2bfloat16(v);
        int d = dg * 32 + tx;
        xp0b[((size_t)b * L_ + p) * D_ + d] = vb;
        int hh = p >> 6, ww = p & 63;
        int r = ww * 64 + hh;   // l1 index
        xp1b[((size_t)b * L_ + r) * D_ + d] = vb;
    }
}

// ---------------------------------------------------------------------------
// Kernel 2 (MFMA): x_dbl[b,k,l,c] = sum_d xs[b,k,d,l] * W[k,c,d]
// ---------------------------------------------------------------------------
__global__ __launch_bounds__(256) void k_proj(const bf16* __restrict__ xp0b,
                                              const bf16* __restrict__ xp1b,
                                              const float* __restrict__ Wp,   // (K,38,192) f32
                                              float* __restrict__ xdbl) {     // (B,K,L,CP)
    __shared__ __align__(16) unsigned short xt[64 * 200];
    __shared__ __align__(16) unsigned short wt[48 * 200];
    int blk  = blockIdx.x;
    int tile = blk & 63;
    int bk   = blk >> 6;
    int k    = bk & 3;
    int b    = bk >> 2;
    const bf16* xpb = (k & 1) ? xp1b : xp0b;
    int g0 = (k < 2) ? tile * 64 : (L_ - 64 - tile * 64);

    unsigned* wtu = (unsigned*)wt;
    for (int i = threadIdx.x; i < 1000; i += 256) wtu[3800 + i] = 0u;
    const float2* wsrc = (const float2*)(Wp + (size_t)k * C_ * D_);
    for (int i = threadIdx.x; i < 3648; i += 256) {   // 38*96 float2
        float2 wv2 = wsrc[i];
        int c = i / 96, dp = i % 96;
        bf16 b0 = __float2bfloat16(wv2.x), b1 = __float2bfloat16(wv2.y);
        unsigned pack = ((unsigned)(*(unsigned short*)&b1) << 16) |
                        (unsigned)(*(unsigned short*)&b0);
        wtu[c * 100 + dp] = pack;
    }
    const uint4* src = (const uint4*)(xpb + ((size_t)b * L_ + g0) * D_);
    for (int i = threadIdx.x; i < 1536; i += 256) {
        uint4 v = src[i];
        int row = i / 24, cg = i % 24;
        int rr = (k < 2) ? row : 63 - row;
        *((uint4*)(xt + rr * 200 + cg * 8)) = v;
    }
    __syncthreads();

    int wv   = threadIdx.x >> 6;
    int lane = threadIdx.x & 63;
    int m0   = wv * 16;
    int mrow = lane & 15;
    int kq   = lane >> 4;

    f32x4 acc[3];
    #pragma unroll
    for (int nt = 0; nt < 3; nt++) acc[nt] = (f32x4){0.f, 0.f, 0.f, 0.f};

    const unsigned short* arow = xt + (m0 + mrow) * 200 + kq * 8;
    const unsigned short* brow = wt + mrow * 200 + kq * 8;
    #pragma unroll
    for (int kt = 0; kt < 6; kt++) {
        v8s af = *(const v8s*)(arow + kt * 32);
        #pragma unroll
        for (int nt = 0; nt < 3; nt++) {
            v8s bf = *(const v8s*)(brow + nt * 16 * 200 + kt * 32);
            acc[nt] = __builtin_amdgcn_mfma_f32_16x16x32_bf16(af, bf, acc[nt], 0, 0, 0);
        }
    }

    int l0g = tile * 64;
    #pragma unroll
    for (int nt = 0; nt < 3; nt++) {
        int c = nt * 16 + mrow;
        if (c < C_) {
            #pragma unroll
            for (int r = 0; r < 4; r++) {
                int m = m0 + kq * 4 + r;
                xdbl[((size_t)bk * L_ + l0g + m) * CP + c] = acc[nt][r];
            }
        }
    }
}

// ---------------------------------------------------------------------------
// Kernel 3 (scanA): ONE scan pass from h=0 per chunk. Emits
// y_local = C.h_local + Ds*u (bf16) and chunk summary P=exp(A*S_64), Hloc.
// No S store — k_corr recomputes S from xdbl (bit-identical f32 sequence).
//
// Final model after 12 experiments: per-wave SERIAL issue = ~130cy VALU +
// 18 trans x 16cy = ~412 cy/step (matches VALUBusy x dur == 66 µs across
// ALL load-path/occupancy/pk variants; R10 proved trans+VALU additive).
// The ~213 cy/step residual is the SMEM lgkmcnt(0) drain (unordered s_load
// returns force full drains), amortized over unroll-2 and SGPR-capped from
// going deeper. Structural floor ~100 µs for this formulation.
// ---------------------------------------------------------------------------
__global__ __launch_bounds__(192) void k_scanA(const float* __restrict__ xdbl,
                                               const bf16* __restrict__ xp0b,
                                               const bf16* __restrict__ xp1b,
                                               const float* __restrict__ dtw,   // (K,D,R)
                                               const float* __restrict__ dtb,   // (K,D)
                                               const float* __restrict__ Alog,  // (K*D,N)
                                               const float* __restrict__ Dsk,   // (K*D,)
                                               bf16* __restrict__ Pst,
                                               bf16* __restrict__ Hloc,
                                               bf16* __restrict__ ys) {         // (B,K,L,D)
    __shared__ __align__(16) unsigned short ut[CL_ * D_];  // 24.6 KB
    int blk = blockIdx.x;
    int c   = blk & (NC_ - 1);
    int bk  = blk >> 6;
    int k   = bk & 3;
    int b   = bk >> 2;
    int d   = threadIdx.x;

    int l0 = c * CL_;
    const bf16* xpb = (k & 1) ? xp1b : xp0b;
    int base_lu = (k < 2) ? l0 : (L_ - CL_ - l0);
    {
        const uint4* usrc = (const uint4*)(xpb + ((size_t)b * L_ + base_lu) * D_);
        uint4* udst = (uint4*)ut;
        #pragma unroll
        for (int i = 0; i < 8; i++) udst[threadIdx.x + i * 192] = usrc[threadIdx.x + i * 192];
    }

    v2f A2[8];     // A * log2(e) pairs, for exp2
    #pragma unroll
    for (int i = 0; i < 8; i++) {
        A2[i].x = -__expf(Alog[((size_t)(k * D_ + d)) * N_ + 2*i])   * 1.44269504f;
        A2[i].y = -__expf(Alog[((size_t)(k * D_ + d)) * N_ + 2*i+1]) * 1.44269504f;
    }
    float wr[R_];
    #pragma unroll
    for (int r = 0; r < R_; r++) wr[r] = dtw[(k * D_ + d) * R_ + r];
    float bias = dtb[k * D_ + d];
    float DsV  = Dsk[k * D_ + d];

    v2f h[8];
    #pragma unroll
    for (int i = 0; i < 8; i++) { h[i].x = 0.f; h[i].y = 0.f; }
    float S = 0.f;
    const float* rb = xdbl + ((size_t)bk * L_ + l0) * CP;
    bf16* yp  = ys   + ((size_t)bk * L_ + l0) * D_ + d;

    int uidx  = ((k < 2) ? 0 : (CL_ - 1)) * D_ + d;
    int ustep = (k < 2) ? D_ : -D_;
    __syncthreads();

    #pragma unroll 2
    for (int s = 0; s < CL_; s++) {
        const float4* r4 = (const float4*)(rb + s * CP);   // block-uniform -> s_load
        float4 q0 = r4[0], q1 = r4[1], q2 = r4[2], q3 = r4[3], q4 = r4[4];
        float4 q5 = r4[5], q6 = r4[6], q7 = r4[7], q8 = r4[8], q9 = r4[9];
        float dpre = bias + wr[0]*q0.x + wr[1]*q0.y + wr[2]*q0.z + wr[3]*q0.w
                          + wr[4]*q1.x + wr[5]*q1.y;
        float delta = softplus_f(dpre);
        float u = bflo(ut[uidx]);  uidx += ustep;          // ds_read_u16
        float du = delta * u;
        S += delta;
        v2f Bv[8] = {{q1.z,q1.w},{q2.x,q2.y},{q2.z,q2.w},{q3.x,q3.y},
                     {q3.z,q3.w},{q4.x,q4.y},{q4.z,q4.w},{q5.x,q5.y}};
        v2f Cv[8] = {{q5.z,q5.w},{q6.x,q6.y},{q6.z,q6.w},{q7.x,q7.y},
                     {q7.z,q7.w},{q8.x,q8.y},{q8.z,q8.w},{q9.x,q9.y}};
        v2f dl2; dl2.x = delta; dl2.y = delta;
        v2f du2; du2.x = du;    du2.y = du;
        v2f y2; y2.x = 0.f; y2.y = 0.f;
        #pragma unroll
        for (int i = 0; i < 8; i++) {
            v2f t = A2[i] * dl2;
            v2f dA;
            dA.x = __builtin_amdgcn_exp2f(t.x);
            dA.y = __builtin_amdgcn_exp2f(t.y);
            v2f bdu = Bv[i] * du2;
            h[i] = __builtin_elementwise_fma(dA, h[i], bdu);   // v_pk_fma_f32
            y2   = __builtin_elementwise_fma(h[i], Cv[i], y2); // v_pk_fma_f32
        }
        float y = y2.x + y2.y;
        *yp = __float2bfloat16(y + u * DsV);
        yp += D_;
    }
    size_t o = ((size_t)blk * D_ + d) * N_;   // blk == bk*NC_ + c
    #pragma unroll
    for (int i = 0; i < 8; i++) {
        v2f t = A2[i] * S;
        Pst[o + 2*i]   = __float2bfloat16(__builtin_amdgcn_exp2f(t.x));
        Pst[o + 2*i+1] = __float2bfloat16(__builtin_amdgcn_exp2f(t.y));
        Hloc[o + 2*i]   = __float2bfloat16(h[i].x);
        Hloc[o + 2*i+1] = __float2bfloat16(h[i].y);
    }
}

// ---------------------------------------------------------------------------
// Kernel 4 (pass 2): chunk-prefix scan over NC_ chunks per (b,k,d,n).
// R12: full unroll. 384 blocks = 1.5 blocks/CU -> zero TLP to hide latency;
// the hh chain is serial but the P/H loads are hh-independent with affine
// addresses, so a full unroll lets the scheduler hoist loads far ahead of
// use instead of one load-use round trip (L2/L3 ~500cy) per iteration.
// ---------------------------------------------------------------------------
__global__ __launch_bounds__(256) void k_pass2(const bf16* __restrict__ Pst,
                                               const bf16* __restrict__ Hloc,
                                               bf16* __restrict__ Hin) {
    int idx = blockIdx.x * 256 + threadIdx.x;   // over B*K*D*N
    int bk  = idx / (D_ * N_);
    int dn  = idx % (D_ * N_);
    float hh = 0.f;
    #pragma unroll
    for (int c = 0; c < NC_; c++) {
        size_t o = ((size_t)bk * NC_ + c) * (D_ * N_) + dn;
        Hin[o] = __float2bfloat16(hh);
        hh = __bfloat162float(Pst[o]) * hh + __bfloat162float(Hloc[o]);
    }
}

// ---------------------------------------------------------------------------
// Kernel 5 (corr): ys += C_l . (exp(A*S_l) * h_in). S is recomputed from
// xdbl's dt columns (scalar-prefetch path; bit-identical to scanA) — no
// per-step vector-load dependency. Per-wave ballot exits the dead tail early
// (threshold 2^-13; tail-sum error bound ~4e-3 vs absmax margin 0.117).
// ---------------------------------------------------------------------------
__global__ __launch_bounds__(192) void k_corr(const float* __restrict__ xdbl,
                                              const float* __restrict__ dtw,   // (K,D,R)
                                              const float* __restrict__ dtb,   // (K,D)
                                              const float* __restrict__ Alog,
                                              const bf16* __restrict__ Hin,
                                              bf16* __restrict__ ys) {
    int blk = blockIdx.x;
    int c   = blk & (NC_ - 1);
    if (c == 0) return;                        // h_in == 0 for first chunk
    int bk  = blk >> 6;
    int k   = bk & 3;
    int d   = threadIdx.x;

    v2f A22[8];
    float aMax = -1e30f;
    #pragma unroll
    for (int i = 0; i < 8; i++) {
        float a0 = -__expf(Alog[((size_t)(k * D_ + d)) * N_ + 2*i])   * 1.44269504f;
        float a1 = -__expf(Alog[((size_t)(k * D_ + d)) * N_ + 2*i+1]) * 1.44269504f;
        A22[i].x = a0; A22[i].y = a1;
        aMax = fmaxf(aMax, fmaxf(a0, a1));
    }
    float wr[R_];
    #pragma unroll
    for (int r = 0; r < R_; r++) wr[r] = dtw[(k * D_ + d) * R_ + r];
    float bias = dtb[k * D_ + d];

    v2f g2[8];
    size_t o = ((size_t)blk * D_ + d) * N_;
    #pragma unroll
    for (int i = 0; i < 8; i++) {
        g2[i].x = __bfloat162float(Hin[o + 2*i]);
        g2[i].y = __bfloat162float(Hin[o + 2*i+1]);
    }

    int l0 = c * CL_;
    const float* rb = xdbl + ((size_t)bk * L_ + l0) * CP;   // block-uniform
    bf16* yp = ys + ((size_t)bk * L_ + l0) * D_ + d;

    float S = 0.f;
    for (int s = 0; s < CL_; s++) {
        const float4* r4 = (const float4*)(rb + s * CP);    // s_load path
        float4 q0 = r4[0], q1 = r4[1];
        float dpre = bias + wr[0]*q0.x + wr[1]*q0.y + wr[2]*q0.z + wr[3]*q0.w
                          + wr[4]*q1.x + wr[5]*q1.y;
        S += softplus_f(dpre);                              // identical to scanA
        bool alive = (aMax * S > -13.f);       // 2^-13 ~ 1.2e-4: below bf16 noise
        if (__ballot(alive) == 0ull) break;
        const float4* c4 = (const float4*)(rb + s * CP + 20);  // C part
        float4 c5 = c4[0], c6 = c4[1], c7 = c4[2], c8 = c4[3], c9 = c4[4];
        v2f C2[8] = {{c5.z,c5.w},{c6.x,c6.y},{c6.z,c6.w},{c7.x,c7.y},
                     {c7.z,c7.w},{c8.x,c8.y},{c8.z,c8.w},{c9.x,c9.y}};
        v2f S2; S2.x = S; S2.y = S;
        v2f acc2; acc2.x = 0.f; acc2.y = 0.f;
        #pragma unroll
        for (int i = 0; i < 8; i++) {
            v2f t = A22[i] * S2;
            v2f e;
            e.x = __builtin_amdgcn_exp2f(t.x);
            e.y = __builtin_amdgcn_exp2f(t.y);
            v2f eg = e * g2[i];
            acc2 = __builtin_elementwise_fma(C2[i], eg, acc2);  // v_pk_fma_f32
        }
        float acc = acc2.x + acc2.y;
        float y = __bfloat162float(*yp) + acc;
        *yp = __float2bfloat16(y);
        yp += D_;
    }
}

// ---------------------------------------------------------------------------
// Kernel 6: cross-merge (4 directions) + LayerNorm over D, output (B,H,W,D)
// ---------------------------------------------------------------------------
__global__ __launch_bounds__(192) void k_merge_ln(const bf16* __restrict__ ys,
                                                  const float* __restrict__ gw,
                                                  const float* __restrict__ gb,
                                                  float* __restrict__ out) {
    int p = blockIdx.x & (L_ - 1);
    int b = blockIdx.x >> 12;     // L_ = 4096
    int d = threadIdx.x;
    int hh = p >> 6, ww = p & 63;
    int l1 = ww * 64 + hh;
    size_t base = (size_t)b * K_ * L_ * D_;
    float v = __bfloat162float(ys[base + ((size_t)0 * L_ + p) * D_ + d])
            + __bfloat162float(ys[base + ((size_t)2 * L_ + (L_ - 1 - p)) * D_ + d])
            + __bfloat162float(ys[base + ((size_t)1 * L_ + l1) * D_ + d])
            + __bfloat162float(ys[base + ((size_t)3 * L_ + (L_ - 1 - l1)) * D_ + d]);
    float s1 = v, s2 = v * v;
    #pragma unroll
    for (int off = 32; off; off >>= 1) {
        s1 += __shfl_down(s1, off);
        s2 += __shfl_down(s2, off);
    }
    __shared__ float aS[3], aQ[3];
    int wid = d >> 6, lane = d & 63;
    if (lane == 0) { aS[wid] = s1; aQ[wid] = s2; }
    __syncthreads();
    float ts1 = aS[0] + aS[1] + aS[2];
    float ts2 = aQ[0] + aQ[1] + aQ[2];
    float mean = ts1 * (1.f / 192.f);
    float var  = ts2 * (1.f / 192.f) - mean * mean;
    float inv  = rsqrtf(var + 1e-5f);
    out[((size_t)b * L_ + p) * D_ + d] = (v - mean) * inv * gw[d] + gb[d];
}

// ---------------------------------------------------------------------------
extern "C" void kernel_launch(void* const* d_in, const int* in_sizes, int n_in,
                              void* d_out, int out_size, void* d_ws, size_t ws_size,
                              hipStream_t stream) {
    const float* x    = (const float*)d_in[0];
    const float* Wp   = (const float*)d_in[1];
    const float* dtw  = (const float*)d_in[2];
    const float* dtb  = (const float*)d_in[3];
    const float* Alog = (const float*)d_in[4];
    const float* Dsk  = (const float*)d_in[5];
    const float* gw   = (const float*)d_in[6];
    const float* gb   = (const float*)d_in[7];
    float* out = (float*)d_out;

    char* ws = (char*)d_ws;
    const size_t S1b = (size_t)B_ * L_ * D_ * 2;            // 12.6 MB (xp0b/xp1b)
    const size_t Sx  = (size_t)B_ * K_ * L_ * CP * 4;       // 21.0 MB (xdbl)
    const size_t Ss  = (size_t)B_ * K_ * NC_ * D_ * N_ * 2; // 12.6 MB (P/Hloc/Hin)
    char* p = ws;
    bf16*  xp0b = (bf16*)p;   p += S1b;
    bf16*  xp1b = (bf16*)p;   p += S1b;
    float* xdbl = (float*)p;  p += Sx;
    bf16*  Pst  = (bf16*)p;   p += Ss;
    bf16*  Hloc = (bf16*)p;   p += Ss;
    bf16*  Hin  = (bf16*)p;   p += Ss;
    bf16*  ys   = (bf16*)p;   // 50.3 MB; total ~135 MB

    k_transpose<<<B_ * 6 * 128, 256, 0, stream>>>(x, xp0b, xp1b);
    k_proj<<<B_ * K_ * (L_ / 64), 256, 0, stream>>>(xp0b, xp1b, Wp, xdbl);
    k_scanA<<<B_ * K_ * NC_, 192, 0, stream>>>(xdbl, xp0b, xp1b, dtw, dtb, Alog, Dsk,
                                               Pst, Hloc, ys);
    k_pass2<<<(B_ * K_ * D_ * N_) / 256, 256, 0, stream>>>(Pst, Hloc, Hin);
    k_corr<<<B_ * K_ * NC_, 192, 0, stream>>>(xdbl, dtw, dtb, Alog, Hin, ys);
    k_merge_ln<<<B_ * L_, 192, 0, stream>>>(ys, gw, gb, out);
}